// Round 5
// baseline (622.633 us; speedup 1.0000x reference)
//
#include <hip/hip_runtime.h>
#include <math.h>

#define B_    32
#define HH    56
#define WW_   56
#define C_    192
#define WS_   7
#define SHIFT_ 3
#define HEADS_ 6
#define DH    32
#define N_    49
#define NWIN  2048
#define ROWS  100352
#define HID_  768
#define QKVN  576

typedef __bf16 bfr;
typedef __bf16 bf8 __attribute__((ext_vector_type(8)));
typedef __bf16 bf4 __attribute__((ext_vector_type(4)));
typedef float  f32x4 __attribute__((ext_vector_type(4)));

#define MFMA16(a,b,c) __builtin_amdgcn_mfma_f32_16x16x32_bf16(a,b,c,0,0,0)

// ---- ws layout (bf16 elements) ----
#define OQW   0         // qkvwT [576][192]
#define OPW   110592    // projwT[192][192]
#define OW1   147456    // w1T   [768][192]
#define OW2   294912    // w2T   [192][768]
#define OBM   442368    // bmask [6][64][64col][64row]  TRANSPOSED (bias+mask, pads=-1e30)
#define WTOT  442368
#define BMTOT 1572864   // 6*64*64*64

// ================= k_prep: transpose + fp32->bf16 all weights =================
__global__ __launch_bounds__(256) void k_prep(
    const float* __restrict__ qkvw, const float* __restrict__ projw,
    const float* __restrict__ w1,   const float* __restrict__ w2,
    bfr* __restrict__ wsp)
{
  int idx = blockIdx.x*256 + threadIdx.x;
  if (idx >= WTOT) return;
  if (idx < OPW)      { int i=idx;      int n=i/192, k=i%192; wsp[idx] = (bfr)qkvw[k*QKVN + n]; }
  else if (idx < OW1) { int i=idx-OPW;  int n=i/192, k=i%192; wsp[idx] = (bfr)projw[k*C_ + n]; }
  else if (idx < OW2) { int i=idx-OW1;  int n=i/192, k=i%192; wsp[idx] = (bfr)w1[k*HID_ + n]; }
  else                { int i=idx-OW2;  int n=i/768, k=i%768; wsp[idx] = (bfr)w2[k*C_ + n]; }
}

// ====== k_prep2: bmask[head][wi][col64][row64] = bias + mask, TRANSPOSED (pads -1e30) ======
__global__ __launch_bounds__(256) void k_prep2(
    const float* __restrict__ btab, const int* __restrict__ rel,
    const float* __restrict__ mask, bfr* __restrict__ bm)
{
  int idx = blockIdx.x*256 + threadIdx.x;   // [head][wi][col][row] -- row fastest
  if (idx >= BMTOT) return;
  int row = idx & 63, col = (idx>>6) & 63, wi = (idx>>12) & 63, head = idx>>18;
  float v = -1e30f;
  if (row < N_ && col < N_) {
    int e = row*N_ + col;
    v = btab[rel[e]*HEADS_ + head] + mask[(size_t)wi*N_*N_ + e];
  }
  bm[idx] = (bfr)v;
}

// ================= Kernel 1: 8-wave blocks, wave = (row-tile, head-half) ============
// LDS (bytes):
#define HSP   196
#define SM_HS 0        // bfr hs[64][196]          25088  (LN'd input, persists)
#define SM_QS 25088    // bfr qs[2][64][36]         9216
#define SM_KS 34304    // bfr ks[2][64][36]         9216
#define SM_VT 43520    // bfr vT[2][32][72]         9216
#define SM_P  52736    // bfr P2[2][64][68]        17408  (wave-private rows per (hl,rt))
#define SM_OV 70144    // bfr ov2[64][72]           9216  ([row][hl*36+d])
#define SM_SR 79360    // int srows[64]              256
#define SM1_TOT 79616

__global__ __launch_bounds__(512, 4) void k_attn(
    const float* __restrict__ x,
    const float* __restrict__ n1w, const float* __restrict__ n1b,
    const bfr*   __restrict__ wsp,
    const float* __restrict__ qkvb,
    const float* __restrict__ projb,
    float* __restrict__ out)
{
  __shared__ char smem[SM1_TOT];
  bfr*   hs    = (bfr*)(smem + SM_HS);
  bfr*   qs    = (bfr*)(smem + SM_QS);
  bfr*   ks    = (bfr*)(smem + SM_KS);
  bfr*   vT    = (bfr*)(smem + SM_VT);
  bfr*   P2    = (bfr*)(smem + SM_P);
  bfr*   ov2   = (bfr*)(smem + SM_OV);
  int*   srows = (int*)(smem + SM_SR);
  float* pj    = (float*)smem;   // overlay [64][196] fp32 = 50176 B over hs/qs/ks/vT

  const f32x4 ZERO4 = {0.f, 0.f, 0.f, 0.f};

  int win  = blockIdx.x;
  int tid  = threadIdx.x;
  int lane = tid & 63, wave = tid >> 6;       // 0..7
  int ln15 = lane & 15, quad = lane >> 4;
  int rt   = wave & 3, hl = wave >> 2;        // row-tile / head-half
  int wi   = win & 63;

  // ---- srows + zero hs pad rows (49..63) ----
  if (tid < N_) {
    int bb = win >> 6;
    int wh = wi >> 3, ww = wi & 7;
    int th = tid / WS_, tw = tid % WS_;
    int sh = wh*WS_ + th + SHIFT_; if (sh >= HH) sh -= HH;
    int sw = ww*WS_ + tw + SHIFT_; if (sw >= WW_) sw -= WW_;
    srows[tid] = bb*HH*WW_ + sh*WW_ + sw;
  }
  {
    int* hz = (int*)(hs + 49*HSP);
    for (int i = tid; i < 15*HSP/2; i += 512) hz[i] = 0;
  }
  __syncthreads();
  // ---- LN1 -> hs (one row per wave iter, 8 waves) ----
  for (int r = wave; r < N_; r += 8) {
    const float* xr = x + (size_t)srows[r]*C_;
    float v0 = xr[lane], v1 = xr[lane+64], v2 = xr[lane+128];
    float s = v0+v1+v2, q = v0*v0+v1*v1+v2*v2;
    #pragma unroll
    for (int m = 32; m; m >>= 1) { s += __shfl_xor(s, m); q += __shfl_xor(q, m); }
    float mu = s*(1.f/C_), var = q*(1.f/C_) - mu*mu;
    float rs = rsqrtf(var + 1e-5f);
    hs[r*HSP + lane]     = (bfr)((v0-mu)*rs*n1w[lane]     + n1b[lane]);
    hs[r*HSP + lane+64]  = (bfr)((v1-mu)*rs*n1w[lane+64]  + n1b[lane+64]);
    hs[r*HSP + lane+128] = (bfr)((v2-mu)*rs*n1w[lane+128] + n1b[lane+128]);
  }
  __syncthreads();

  const bfr* qkvwT  = wsp + OQW;
  const bfr* projwT = wsp + OPW;
  const bfr* bmask  = wsp + OBM;

  f32x4 accp[3][4];   // proj partials for this wave's hl (combined in epilogue)
  #pragma unroll
  for (int j=0;j<3;j++)
    #pragma unroll
    for (int mt=0;mt<4;mt++) accp[j][mt] = ZERO4;

  for (int pair = 0; pair < 3; pair++) {
    // ---- QKV: wave computes rows (hl*32..+31) x col-slice rt*16 of q,k,v ----
    {
      float qb[3];
      #pragma unroll
      for (int j=0;j<3;j++) qb[j] = qkvb[j*192 + pair*64 + rt*16 + ln15];
      f32x4 acc[3][2];
      #pragma unroll
      for (int j=0;j<3;j++)
        #pragma unroll
        for (int mtl=0;mtl<2;mtl++) acc[j][mtl] = ZERO4;
      #pragma unroll
      for (int kk = 0; kk < 6; kk++) {
        bf8 afr[2];
        #pragma unroll
        for (int mtl=0;mtl<2;mtl++)
          afr[mtl] = *(const bf8*)&hs[((hl*2+mtl)*16+ln15)*HSP + kk*32 + quad*8];
        #pragma unroll
        for (int j=0;j<3;j++) {
          bf8 bw = *(const bf8*)&qkvwT[(size_t)(j*192 + pair*64 + rt*16 + ln15)*192
                                       + kk*32 + quad*8];
          #pragma unroll
          for (int mtl=0;mtl<2;mtl++) acc[j][mtl] = MFMA16(afr[mtl], bw, acc[j][mtl]);
        }
      }
      int colp = rt*16 + ln15;         // within-pair col 0..63
      int chl = colp >> 5, d = colp & 31;
      #pragma unroll
      for (int j=0;j<3;j++) {
        #pragma unroll
        for (int mtl=0;mtl<2;mtl++)
          #pragma unroll
          for (int r=0;r<4;r++) {
            int row = (hl*2+mtl)*16 + quad*4 + r;
            float vv = acc[j][mtl][r] + qb[j];
            if (j == 0)      qs[(chl*64+row)*36 + d] = (bfr)(vv*0.17677669529663689f);
            else if (j == 1) ks[(chl*64+row)*36 + d] = (bfr)vv;
            else             vT[(chl*32+d)*72 + row] = (bfr)vv;
          }
      }
    }
    __syncthreads();

    int head = pair*2 + hl;
    // ---- bmask burst (this wave's head, 4x 8B loads) ----
    bf4 bm4[4];
    {
      const bfr* bmh = bmask + (((size_t)head*64 + wi) << 12);  // [col64][row64]
      #pragma unroll
      for (int nt = 0; nt < 4; nt++)
        bm4[nt] = *(const bf4*)&bmh[(nt*16 + ln15)*64 + rt*16 + quad*4];
    }

    // ---- QK^T (rows rt*16..+15 of head hl), bias+mask as MFMA C-init ----
    float val[4][4];   // [nt][r]
    {
      bf8 aq = *(const bf8*)&qs[(hl*64 + rt*16 + ln15)*36 + quad*8];
      #pragma unroll
      for (int nt = 0; nt < 4; nt++) {
        f32x4 c;
        c[0] = (float)bm4[nt][0]; c[1] = (float)bm4[nt][1];
        c[2] = (float)bm4[nt][2]; c[3] = (float)bm4[nt][3];
        bf8 bk = *(const bf8*)&ks[(hl*64 + nt*16 + ln15)*36 + quad*8];
        c = MFMA16(aq, bk, c);
        #pragma unroll
        for (int r=0;r<4;r++) val[nt][r] = c[r];
      }
    }

    // ---- proj-weight prefetch (3x 16B): latency hides under softmax ----
    bf8 pw[3];
    #pragma unroll
    for (int j = 0; j < 3; j++)
      pw[j] = *(const bf8*)&projwT[(size_t)((rt*3+j)*16 + ln15)*192 + head*32 + quad*8];

    // ---- register softmax + P2 (wave-private rows, NO barrier) + PV -> ov2 ----
    {
      float mx[4], sum[4];
      #pragma unroll
      for (int r=0;r<4;r++) {
        mx[r] = fmaxf(fmaxf(val[0][r], val[1][r]), fmaxf(val[2][r], val[3][r]));
        #pragma unroll
        for (int m = 1; m < 16; m <<= 1) mx[r] = fmaxf(mx[r], __shfl_xor(mx[r], m));
      }
      #pragma unroll
      for (int nt=0;nt<4;nt++)
        #pragma unroll
        for (int r=0;r<4;r++) val[nt][r] = __expf(val[nt][r] - mx[r]);
      #pragma unroll
      for (int r=0;r<4;r++) {
        sum[r] = val[0][r] + val[1][r] + val[2][r] + val[3][r];
        #pragma unroll
        for (int m = 1; m < 16; m <<= 1) sum[r] += __shfl_xor(sum[r], m);
        sum[r] = 1.f / sum[r];
      }
      #pragma unroll
      for (int nt=0;nt<4;nt++)
        #pragma unroll
        for (int r=0;r<4;r++)
          P2[(hl*64 + rt*16 + quad*4 + r)*68 + nt*16 + ln15] = (bfr)(val[nt][r]*sum[r]);
      // PV: wave reads ONLY its own P2 rows -> in-wave lgkmcnt dep, no barrier
      #pragma unroll
      for (int nt = 0; nt < 2; nt++) {
        f32x4 c = ZERO4;
        #pragma unroll
        for (int k0 = 0; k0 < 64; k0 += 32) {
          bf8 ap = *(const bf8*)&P2[(hl*64 + rt*16 + ln15)*68 + k0 + quad*8];
          bf8 bv = *(const bf8*)&vT[(hl*32 + nt*16 + ln15)*72 + k0 + quad*8];
          c = MFMA16(ap, bv, c);
        }
        #pragma unroll
        for (int r=0;r<4;r++)
          ov2[(rt*16 + quad*4 + r)*72 + hl*36 + nt*16 + ln15] = (bfr)c[r];
      }
    }
    __syncthreads();

    // ---- proj K-step for this wave's head (K=32), weights in regs ----
    {
      bf8 afr[4];
      #pragma unroll
      for (int mt=0;mt<4;mt++)
        afr[mt] = *(const bf8*)&ov2[(mt*16+ln15)*72 + hl*36 + quad*8];
      #pragma unroll
      for (int j=0;j<3;j++)
        #pragma unroll
        for (int mt=0;mt<4;mt++) accp[j][mt] = MFMA16(afr[mt], pw[j], accp[j][mt]);
    }
    // no barrier: next pair's QKV writes qs/ks/vT; all reads of them finished pre-ov2-barrier
  }

  // ---- epilogue: combine hl-halves into pj overlay, then residual+scatter ----
  __syncthreads();   // all waves past last proj before pj overlays hs..vT
  if (hl == 0) {
    #pragma unroll
    for (int j=0;j<3;j++) {
      int col = (rt*3+j)*16 + ln15;
      float pb = projb[col];
      #pragma unroll
      for (int mt=0;mt<4;mt++)
        #pragma unroll
        for (int r=0;r<4;r++)
          pj[(mt*16 + quad*4 + r)*196 + col] = accp[j][mt][r] + pb;
    }
  }
  __syncthreads();
  if (hl == 1) {
    #pragma unroll
    for (int j=0;j<3;j++) {
      int col = (rt*3+j)*16 + ln15;
      #pragma unroll
      for (int mt=0;mt<4;mt++)
        #pragma unroll
        for (int r=0;r<4;r++)
          pj[(mt*16 + quad*4 + r)*196 + col] += accp[j][mt][r];
    }
  }
  __syncthreads();
  for (int idx = tid; idx < N_*C_; idx += 512) {
    int n = idx / C_, c = idx % C_;
    size_t gr = (size_t)srows[n]*C_ + c;
    out[gr] = x[gr] + pj[n*196 + c];
  }
}

// ================= Kernel 2: 8-wave blocks, M=64, 2 chunks of 384 hidden cols =============
// LDS: ts[64][196] bf16 (25088) + hidc[64][392] bf16 (50176) = 75264 B -> 2 blocks/CU,
// 16 waves/CU. st f32[64][196] (50176) overlays ts+hidc after last use.
#define SM2_TS  0
#define SM2_HID 25088
#define SM2_TOT 75264

__global__ __launch_bounds__(512, 4) void k_mlp(
    float* __restrict__ y,
    const float* __restrict__ n2w, const float* __restrict__ n2b,
    const bfr* __restrict__ wsp,
    const float* __restrict__ b1, const float* __restrict__ b2)
{
  __shared__ char smem[SM2_TOT];
  bfr*   ts   = (bfr*)(smem + SM2_TS);
  bfr*   hidc = (bfr*)(smem + SM2_HID);
  float* st   = (float*)smem;       // overlay after ts/hidc dead

  const f32x4 ZERO4 = {0.f, 0.f, 0.f, 0.f};

  int r0 = blockIdx.x * 64;
  int tid = threadIdx.x;
  int lane = tid & 63, wave = tid >> 6;       // 0..7
  int ln15 = lane & 15, quad = lane >> 4;
  int cg = wave & 3, kh = wave >> 2;          // fc2 col-group / K-half

  // ---- LN2 ----
  for (int r = wave; r < 64; r += 8) {
    const float* yr = y + (size_t)(r0 + r)*C_;
    float v0 = yr[lane], v1 = yr[lane+64], v2 = yr[lane+128];
    float s = v0+v1+v2, q = v0*v0+v1*v1+v2*v2;
    #pragma unroll
    for (int m = 32; m; m >>= 1) { s += __shfl_xor(s, m); q += __shfl_xor(q, m); }
    float mu = s*(1.f/C_), var = q*(1.f/C_) - mu*mu;
    float rs = rsqrtf(var + 1e-5f);
    ts[r*HSP + lane]     = (bfr)((v0-mu)*rs*n2w[lane]     + n2b[lane]);
    ts[r*HSP + lane+64]  = (bfr)((v1-mu)*rs*n2w[lane+64]  + n2b[lane+64]);
    ts[r*HSP + lane+128] = (bfr)((v2-mu)*rs*n2w[lane+128] + n2b[lane+128]);
  }
  __syncthreads();

  const bfr* w1T = wsp + OW1;
  const bfr* w2T = wsp + OW2;

  f32x4 accp[3][4];   // fc2 partials for this wave's (cg,kh), combined in epilogue
  #pragma unroll
  for (int j=0;j<3;j++)
    #pragma unroll
    for (int mt=0;mt<4;mt++) accp[j][mt] = ZERO4;

  for (int c = 0; c < 2; c++) {
    // ---- fc1 chunk: M=64, N=384 (this wave: cols c*384 + wave*48 + j*16), K=192 ----
    {
      f32x4 acc[3][4];
      #pragma unroll
      for (int j=0;j<3;j++)
        #pragma unroll
        for (int mt=0;mt<4;mt++) acc[j][mt] = ZERO4;
      float bb[3];
      #pragma unroll
      for (int j=0;j<3;j++) bb[j] = b1[c*384 + wave*48 + j*16 + ln15];
      #pragma unroll
      for (int kk = 0; kk < 6; kk++) {
        bf8 afr[4];
        #pragma unroll
        for (int mt=0;mt<4;mt++)
          afr[mt] = *(const bf8*)&ts[(mt*16+ln15)*HSP + kk*32 + quad*8];
        #pragma unroll
        for (int j=0;j<3;j++) {
          bf8 bw = *(const bf8*)&w1T[(size_t)(c*384 + wave*48 + j*16 + ln15)*192
                                     + kk*32 + quad*8];
          #pragma unroll
          for (int mt=0;mt<4;mt++) acc[j][mt] = MFMA16(afr[mt], bw, acc[j][mt]);
        }
      }
      // GELU (tanh-form sigmoid; |err|<3e-4 << bf16 lsb)
      #pragma unroll
      for (int j=0;j<3;j++) {
        int colc = wave*48 + j*16 + ln15;    // local col within chunk (0..383)
        #pragma unroll
        for (int mt=0;mt<4;mt++)
          #pragma unroll
          for (int r=0;r<4;r++) {
            int row = mt*16 + quad*4 + r;
            float g = acc[j][mt][r] + bb[j];
            float u = g*(1.5957691216f + 0.0713548170f*g*g);
            hidc[row*392 + colc] = (bfr)(g / (1.f + __expf(-u)));
          }
      }
    }
    __syncthreads();
    // ---- fc2 partial: this wave: cols (cg*3+j)*16, K local kh*192 + kk*32 ----
    #pragma unroll
    for (int kk = 0; kk < 6; kk++) {
      bf8 afr[4];
      #pragma unroll
      for (int mt=0;mt<4;mt++)
        afr[mt] = *(const bf8*)&hidc[(mt*16+ln15)*392 + kh*192 + kk*32 + quad*8];
      #pragma unroll
      for (int j=0;j<3;j++) {
        bf8 bw = *(const bf8*)&w2T[(size_t)((cg*3+j)*16 + ln15)*768
                                   + c*384 + kh*192 + kk*32 + quad*8];
        #pragma unroll
        for (int mt=0;mt<4;mt++) accp[j][mt] = MFMA16(afr[mt], bw, accp[j][mt]);
      }
    }
    __syncthreads();   // hidc reads done before next chunk's writes (or st overlay)
  }

  // ---- epilogue: combine K-halves into st overlay (over ts/hidc, both dead) ----
  if (kh == 0) {
    #pragma unroll
    for (int j=0;j<3;j++) {
      int col = (cg*3+j)*16 + ln15;
      float bb2 = b2[col];
      #pragma unroll
      for (int mt=0;mt<4;mt++)
        #pragma unroll
        for (int r=0;r<4;r++)
          st[(mt*16 + quad*4 + r)*196 + col] = accp[j][mt][r] + bb2;
    }
  }
  __syncthreads();
  if (kh == 1) {
    #pragma unroll
    for (int j=0;j<3;j++) {
      int col = (cg*3+j)*16 + ln15;
      #pragma unroll
      for (int mt=0;mt<4;mt++)
        #pragma unroll
        for (int r=0;r<4;r++)
          st[(mt*16 + quad*4 + r)*196 + col] += accp[j][mt][r];
    }
  }
  __syncthreads();
  // residual, coalesced, in-place
  for (int idx = tid; idx < 64*C_; idx += 512) {
    int r = idx / C_, c = idx % C_;
    size_t gr = (size_t)(r0 + r)*C_ + c;
    y[gr] = y[gr] + st[r*196 + c];
  }
}

extern "C" void kernel_launch(void* const* d_in, const int* in_sizes, int n_in,
                              void* d_out, int out_size, void* d_ws, size_t ws_size,
                              hipStream_t stream) {
  const float* x     = (const float*)d_in[0];
  const float* n1w   = (const float*)d_in[1];
  const float* n1b   = (const float*)d_in[2];
  const float* qkvw  = (const float*)d_in[3];
  const float* qkvb  = (const float*)d_in[4];
  const float* btab  = (const float*)d_in[5];
  const float* projw = (const float*)d_in[6];
  const float* projb = (const float*)d_in[7];
  const float* n2w   = (const float*)d_in[8];
  const float* n2b   = (const float*)d_in[9];
  const float* w1    = (const float*)d_in[10];
  const float* b1    = (const float*)d_in[11];
  const float* w2    = (const float*)d_in[12];
  const float* b2    = (const float*)d_in[13];
  const float* mask  = (const float*)d_in[14];
  const int*   rel   = (const int*)d_in[15];
  float* out = (float*)d_out;
  bfr*   wsp = (bfr*)d_ws;   // (442368 + 1572864) * 2 B ~= 4.03 MB

  k_prep<<<(WTOT+255)/256, 256, 0, stream>>>(qkvw, projw, w1, w2, wsp);
  k_prep2<<<(BMTOT+255)/256, 256, 0, stream>>>(btab, rel, mask, wsp + OBM);
  k_attn<<<NWIN, 512, 0, stream>>>(x, n1w, n1b, wsp, qkvb, projb, out);
  k_mlp<<<ROWS/64, 512, 0, stream>>>(out, n2w, n2b, wsp, b1, b2);
}

// Round 6
// 535.917 us; speedup vs baseline: 1.1618x; 1.1618x over previous
//
#include <hip/hip_runtime.h>
#include <math.h>

#define B_    32
#define HH    56
#define WW_   56
#define C_    192
#define WS_   7
#define SHIFT_ 3
#define HEADS_ 6
#define DH    32
#define N_    49
#define NWIN  2048
#define ROWS  100352
#define HID_  768
#define QKVN  576

typedef __bf16 bfr;
typedef __bf16 bf8 __attribute__((ext_vector_type(8)));
typedef __bf16 bf4 __attribute__((ext_vector_type(4)));
typedef float  f32x4 __attribute__((ext_vector_type(4)));

#define MFMA16(a,b,c) __builtin_amdgcn_mfma_f32_16x16x32_bf16(a,b,c,0,0,0)

// ---- ws layout (bf16 elements) ----
#define OQW   0         // qkvwT [576][192]
#define OPW   110592    // projwT[192][192]
#define OW1   147456    // w1T   [768][192]
#define OW2   294912    // w2T   [192][768]
#define OBM   442368    // bmask [6][4cls][64col][64row] TRANSPOSED (bias+mask, pads=-1e30)
#define WTOT  442368
#define BMTOT 98304     // 6*4*64*64  (4 window classes: (wh==7)x(ww==7))

// ================= k_prep: transpose + fp32->bf16 all weights =================
__global__ __launch_bounds__(256) void k_prep(
    const float* __restrict__ qkvw, const float* __restrict__ projw,
    const float* __restrict__ w1,   const float* __restrict__ w2,
    bfr* __restrict__ wsp)
{
  int idx = blockIdx.x*256 + threadIdx.x;
  if (idx >= WTOT) return;
  if (idx < OPW)      { int i=idx;      int n=i/192, k=i%192; wsp[idx] = (bfr)qkvw[k*QKVN + n]; }
  else if (idx < OW1) { int i=idx-OPW;  int n=i/192, k=i%192; wsp[idx] = (bfr)projw[k*C_ + n]; }
  else if (idx < OW2) { int i=idx-OW1;  int n=i/192, k=i%192; wsp[idx] = (bfr)w1[k*HID_ + n]; }
  else                { int i=idx-OW2;  int n=i/768, k=i%768; wsp[idx] = (bfr)w2[k*C_ + n]; }
}

// ====== k_prep2: bmask[head][cls][col64][row64] = bias + mask (pads -1e30) ======
// The shifted-window mask pattern depends on (wh,ww) ONLY through (wh==7, ww==7):
// 4 classes. Representative windows: cls0->wi0, cls1->wi7, cls2->wi56, cls3->wi63.
__global__ __launch_bounds__(256) void k_prep2(
    const float* __restrict__ btab, const int* __restrict__ rel,
    const float* __restrict__ mask, bfr* __restrict__ bm)
{
  int idx = blockIdx.x*256 + threadIdx.x;   // [head][cls][col][row] -- row fastest
  if (idx >= BMTOT) return;
  int row = idx & 63, col = (idx>>6) & 63, cls = (idx>>12) & 3, head = idx>>14;
  int wh = (cls & 2) ? 7 : 0, ww = (cls & 1) ? 7 : 0;
  int wi = wh*8 + ww;
  float v = -1e30f;
  if (row < N_ && col < N_) {
    int e = row*N_ + col;
    v = btab[rel[e]*HEADS_ + head] + mask[(size_t)wi*N_*N_ + e];
  }
  bm[idx] = (bfr)v;
}

// ================= Kernel 1: LN1+shift+QKV+attn+proj+residual, head-pair fused ============
// LDS (bytes):
#define SM_HS 0        // bfr hs[64][200]          25600  (LN'd input, persists)
#define SM_QS 25600    // bfr qs[2][64][36]         9216
#define SM_KS 34816    // bfr ks[2][64][36]         9216
#define SM_VT 44032    // bfr vT[2][32][72]         9216
#define SM_P  53248    // bfr P[64][72]             9216  (wave-row-local scratch)
#define SM_OV 62464    // bfr ov2[64][72]           9216  (both heads: [row][hl*36+d])
#define SM_SR 71680    // int srows[64]              256
#define SM1_TOT 71936
#define HSP 200

__global__ __launch_bounds__(256, 2) void k_attn(
    const float* __restrict__ x,
    const float* __restrict__ n1w, const float* __restrict__ n1b,
    const bfr*   __restrict__ wsp,
    const float* __restrict__ qkvb,
    const float* __restrict__ projb,
    float* __restrict__ out)
{
  __shared__ char smem[SM1_TOT];
  bfr*   hs    = (bfr*)(smem + SM_HS);
  bfr*   qs    = (bfr*)(smem + SM_QS);
  bfr*   ks    = (bfr*)(smem + SM_KS);
  bfr*   vT    = (bfr*)(smem + SM_VT);
  bfr*   P     = (bfr*)(smem + SM_P);
  bfr*   ov2   = (bfr*)(smem + SM_OV);
  int*   srows = (int*)(smem + SM_SR);
  float* pj    = (float*)smem;   // overlay [64][196] fp32 = 50176 B over hs/qs/ks/vT

  const f32x4 ZERO4 = {0.f, 0.f, 0.f, 0.f};

  int win  = blockIdx.x;
  int tid  = threadIdx.x;
  int lane = tid & 63, wave = tid >> 6;
  int ln15 = lane & 15, quad = lane >> 4;
  int wi   = win & 63;
  int cls  = (((wi>>3)==7) ? 2 : 0) + (((wi&7)==7) ? 1 : 0);

  // ---- srows + zero hs pad rows (49..63 only) ----
  if (tid < N_) {
    int bb = win >> 6;
    int wh = wi >> 3, ww = wi & 7;
    int th = tid / WS_, tw = tid % WS_;
    int sh = wh*WS_ + th + SHIFT_; if (sh >= HH) sh -= HH;
    int sw = ww*WS_ + tw + SHIFT_; if (sw >= WW_) sw -= WW_;
    srows[tid] = bb*HH*WW_ + sh*WW_ + sw;
  }
  {
    int* hz = (int*)(hs + 49*HSP);
    for (int i = tid; i < 15*HSP/2; i += 256) hz[i] = 0;
  }
  __syncthreads();
  // ---- LN1 -> hs, keep x rows in registers for residual epilogue ----
  float xv0[13], xv1[13], xv2[13];
  #pragma unroll
  for (int i = 0; i < 13; i++) {
    int r = wave + i*4;
    if (r < N_) {
      const float* xr = x + (size_t)srows[r]*C_;
      float v0 = xr[lane], v1 = xr[lane+64], v2 = xr[lane+128];
      xv0[i] = v0; xv1[i] = v1; xv2[i] = v2;
      float s = v0+v1+v2, q = v0*v0+v1*v1+v2*v2;
      #pragma unroll
      for (int m = 32; m; m >>= 1) { s += __shfl_xor(s, m); q += __shfl_xor(q, m); }
      float mu = s*(1.f/C_), var = q*(1.f/C_) - mu*mu;
      float rs = rsqrtf(var + 1e-5f);
      hs[r*HSP + lane]     = (bfr)((v0-mu)*rs*n1w[lane]     + n1b[lane]);
      hs[r*HSP + lane+64]  = (bfr)((v1-mu)*rs*n1w[lane+64]  + n1b[lane+64]);
      hs[r*HSP + lane+128] = (bfr)((v2-mu)*rs*n1w[lane+128] + n1b[lane+128]);
    }
  }
  __syncthreads();

  const bfr* qkvwT  = wsp + OQW;
  const bfr* projwT = wsp + OPW;
  const bfr* bmask  = wsp + OBM;

  f32x4 accp[3][4];   // proj accumulators, persist across pairs
  #pragma unroll
  for (int j=0;j<3;j++)
    #pragma unroll
    for (int mt=0;mt<4;mt++) accp[j][mt] = ZERO4;

  for (int pair = 0; pair < 3; pair++) {
    // ---- QKV phase: wave handles col-tile (wave) of q(j=0),k(j=1),v(j=2) ----
    {
      float qb[3];
      #pragma unroll
      for (int j=0;j<3;j++) qb[j] = qkvb[j*192 + pair*64 + wave*16 + ln15];
      f32x4 acc[3][4];
      #pragma unroll
      for (int j=0;j<3;j++)
        #pragma unroll
        for (int mt=0;mt<4;mt++) acc[j][mt] = ZERO4;
      #pragma unroll
      for (int kk = 0; kk < 6; kk++) {
        bf8 afr[4];
        #pragma unroll
        for (int mt=0;mt<4;mt++)
          afr[mt] = *(const bf8*)&hs[(mt*16+ln15)*HSP + kk*32 + quad*8];
        #pragma unroll
        for (int j=0;j<3;j++) {
          bf8 bw = *(const bf8*)&qkvwT[(size_t)(j*192 + pair*64 + wave*16 + ln15)*192
                                       + kk*32 + quad*8];
          #pragma unroll
          for (int mt=0;mt<4;mt++) acc[j][mt] = MFMA16(afr[mt], bw, acc[j][mt]);
        }
      }
      int colp = wave*16 + ln15;         // within-pair col 0..63
      int hl = colp >> 5, d = colp & 31;
      #pragma unroll
      for (int j=0;j<3;j++) {
        #pragma unroll
        for (int mt=0;mt<4;mt++)
          #pragma unroll
          for (int r=0;r<4;r++) {
            int row = mt*16 + quad*4 + r;
            float vv = acc[j][mt][r] + qb[j];
            if (j == 0)      qs[(hl*64+row)*36 + d] = (bfr)(vv*0.17677669529663689f);
            else if (j == 1) ks[(hl*64+row)*36 + d] = (bfr)vv;
            else             vT[(hl*32+d)*72 + row] = (bfr)vv;
          }
      }
    }
    __syncthreads();

    // ---- bmask burst (both heads, 8x 8B loads; table is 192KB -> L2-resident) ----
    bf4 bm4[2][4];
    #pragma unroll
    for (int hl = 0; hl < 2; hl++) {
      const bfr* bmh = bmask + (((size_t)(pair*2+hl)*4 + cls) << 12);  // [col64][row64]
      #pragma unroll
      for (int nt = 0; nt < 4; nt++)
        bm4[hl][nt] = *(const bf4*)&bmh[(nt*16 + ln15)*64 + wave*16 + quad*4];
    }

    // ---- QK^T for BOTH heads, bias+mask as MFMA C-init ----
    float val[2][4][4];   // [hl][nt][r]
    #pragma unroll
    for (int hl = 0; hl < 2; hl++) {
      bf8 aq = *(const bf8*)&qs[(hl*64 + wave*16 + ln15)*36 + quad*8];
      #pragma unroll
      for (int nt = 0; nt < 4; nt++) {
        f32x4 c;
        c[0] = (float)bm4[hl][nt][0]; c[1] = (float)bm4[hl][nt][1];
        c[2] = (float)bm4[hl][nt][2]; c[3] = (float)bm4[hl][nt][3];
        bf8 bk = *(const bf8*)&ks[(hl*64 + nt*16 + ln15)*36 + quad*8];
        c = MFMA16(aq, bk, c);
        #pragma unroll
        for (int r=0;r<4;r++) val[hl][nt][r] = c[r];
      }
    }

    // ---- proj-weight prefetch (6x 16B): latency hides under softmax ----
    bf8 pw[2][3];
    #pragma unroll
    for (int hl = 0; hl < 2; hl++)
      #pragma unroll
      for (int j = 0; j < 3; j++)
        pw[hl][j] = *(const bf8*)&projwT[(size_t)((wave*3+j)*16 + ln15)*192
                                         + (pair*2+hl)*32 + quad*8];

    // ---- per head: register softmax + P (wave-row-local, NO barrier) + PV -> ov2 ----
    #pragma unroll
    for (int hl = 0; hl < 2; hl++) {
      float mx[4], sum[4];
      #pragma unroll
      for (int r=0;r<4;r++) {
        mx[r] = fmaxf(fmaxf(val[hl][0][r], val[hl][1][r]), fmaxf(val[hl][2][r], val[hl][3][r]));
        #pragma unroll
        for (int m = 1; m < 16; m <<= 1) mx[r] = fmaxf(mx[r], __shfl_xor(mx[r], m));
      }
      #pragma unroll
      for (int nt=0;nt<4;nt++)
        #pragma unroll
        for (int r=0;r<4;r++) val[hl][nt][r] = __expf(val[hl][nt][r] - mx[r]);
      #pragma unroll
      for (int r=0;r<4;r++) {
        sum[r] = val[hl][0][r] + val[hl][1][r] + val[hl][2][r] + val[hl][3][r];
        #pragma unroll
        for (int m = 1; m < 16; m <<= 1) sum[r] += __shfl_xor(sum[r], m);
        sum[r] = 1.f / sum[r];
      }
      #pragma unroll
      for (int nt=0;nt<4;nt++)
        #pragma unroll
        for (int r=0;r<4;r++)
          P[(wave*16 + quad*4 + r)*72 + nt*16 + ln15] = (bfr)(val[hl][nt][r]*sum[r]);
      // PV: wave reads ONLY its own P rows -> in-wave lgkmcnt dep, no barrier
      #pragma unroll
      for (int nt = 0; nt < 2; nt++) {
        f32x4 c = ZERO4;
        #pragma unroll
        for (int k0 = 0; k0 < 64; k0 += 32) {
          bf8 ap = *(const bf8*)&P[(wave*16 + ln15)*72 + k0 + quad*8];
          bf8 bv = *(const bf8*)&vT[(hl*32 + nt*16 + ln15)*72 + k0 + quad*8];
          c = MFMA16(ap, bv, c);
        }
        #pragma unroll
        for (int r=0;r<4;r++)
          ov2[(wave*16 + quad*4 + r)*72 + hl*36 + nt*16 + ln15] = (bfr)c[r];
      }
    }
    __syncthreads();

    // ---- proj K-step for this pair (K=64: both heads), weights already in regs ----
    #pragma unroll
    for (int hl = 0; hl < 2; hl++) {
      bf8 afr[4];
      #pragma unroll
      for (int mt=0;mt<4;mt++)
        afr[mt] = *(const bf8*)&ov2[(mt*16+ln15)*72 + hl*36 + quad*8];
      #pragma unroll
      for (int j=0;j<3;j++)
        #pragma unroll
        for (int mt=0;mt<4;mt++) accp[j][mt] = MFMA16(afr[mt], pw[hl][j], accp[j][mt]);
    }
    // no barrier: next pair's QKV writes qs/ks/vT; all reads of them finished pre-ov2-barrier
  }

  // ---- epilogue: bias -> pj overlay -> residual (from regs) + scatter ----
  __syncthreads();   // all waves past last proj before pj overlays hs..vT
  #pragma unroll
  for (int j=0;j<3;j++) {
    int col = (wave*3+j)*16 + ln15;
    float pb = projb[col];
    #pragma unroll
    for (int mt=0;mt<4;mt++)
      #pragma unroll
      for (int r=0;r<4;r++)
        pj[(mt*16 + quad*4 + r)*196 + col] = accp[j][mt][r] + pb;
  }
  __syncthreads();
  #pragma unroll
  for (int i = 0; i < 13; i++) {
    int r = wave + i*4;
    if (r < N_) {
      float* orow = out + (size_t)srows[r]*C_;
      orow[lane]     = xv0[i] + pj[r*196 + lane];
      orow[lane+64]  = xv1[i] + pj[r*196 + lane+64];
      orow[lane+128] = xv2[i] + pj[r*196 + lane+128];
    }
  }
}

// ================= Kernel 2: LN2 + fc1 + GELU + fc2 + residual, 64 rows/block ================
// Double-buffered hidden chunk: one barrier per chunk (fc1(c+1) overlaps fc2(c)).
// LDS: ts[64][200] (25600) + hid[2][64][200] (51200) = 76800 B -> 2 blocks/CU.
// st f32[64][196] (50176) overlays ts+hid[0] after their last reads (guarded by barrier(3)).
#define SM2_TS  0
#define SM2_H0  25600
#define SM2_TOT 76800

__global__ __launch_bounds__(256, 2) void k_mlp(
    float* __restrict__ y,
    const float* __restrict__ n2w, const float* __restrict__ n2b,
    const bfr* __restrict__ wsp,
    const float* __restrict__ b1, const float* __restrict__ b2)
{
  __shared__ char smem[SM2_TOT];
  bfr*   ts  = (bfr*)(smem + SM2_TS);
  float* st  = (float*)smem;       // overlay after ts/hid0 dead

  const f32x4 ZERO4 = {0.f, 0.f, 0.f, 0.f};

  int r0 = blockIdx.x * 64;
  int tid = threadIdx.x;
  int lane = tid & 63, wave = tid >> 6;
  int ln15 = lane & 15, quad = lane >> 4;

  // ---- LN2 ----
  for (int r = wave; r < 64; r += 4) {
    const float* yr = y + (size_t)(r0 + r)*C_;
    float v0 = yr[lane], v1 = yr[lane+64], v2 = yr[lane+128];
    float s = v0+v1+v2, q = v0*v0+v1*v1+v2*v2;
    #pragma unroll
    for (int m = 32; m; m >>= 1) { s += __shfl_xor(s, m); q += __shfl_xor(q, m); }
    float mu = s*(1.f/C_), var = q*(1.f/C_) - mu*mu;
    float rs = rsqrtf(var + 1e-5f);
    ts[r*HSP + lane]     = (bfr)((v0-mu)*rs*n2w[lane]     + n2b[lane]);
    ts[r*HSP + lane+64]  = (bfr)((v1-mu)*rs*n2w[lane+64]  + n2b[lane+64]);
    ts[r*HSP + lane+128] = (bfr)((v2-mu)*rs*n2w[lane+128] + n2b[lane+128]);
  }
  __syncthreads();

  const bfr* w1T = wsp + OW1;
  const bfr* w2T = wsp + OW2;

  f32x4 accp[3][4];   // fc2 accumulators, persist across chunks
  #pragma unroll
  for (int j=0;j<3;j++)
    #pragma unroll
    for (int mt=0;mt<4;mt++) accp[j][mt] = ZERO4;

  for (int c = 0; c < 4; c++) {
    bfr* hidc = (bfr*)(smem + SM2_H0 + (c & 1)*25600);
    // ---- fc1 chunk: M=64, N=192 (cols c*192..+191), K=192 ----
    {
      f32x4 acc[3][4];
      #pragma unroll
      for (int j=0;j<3;j++)
        #pragma unroll
        for (int mt=0;mt<4;mt++) acc[j][mt] = ZERO4;
      float bb[3];
      #pragma unroll
      for (int j=0;j<3;j++) bb[j] = b1[c*192 + (wave*3+j)*16 + ln15];
      #pragma unroll
      for (int kk = 0; kk < 6; kk++) {
        bf8 afr[4];
        #pragma unroll
        for (int mt=0;mt<4;mt++)
          afr[mt] = *(const bf8*)&ts[(mt*16+ln15)*HSP + kk*32 + quad*8];
        #pragma unroll
        for (int j=0;j<3;j++) {
          bf8 bw = *(const bf8*)&w1T[(size_t)((c*12 + wave*3 + j)*16 + ln15)*192
                                     + kk*32 + quad*8];
          #pragma unroll
          for (int mt=0;mt<4;mt++) acc[j][mt] = MFMA16(afr[mt], bw, acc[j][mt]);
        }
      }
      // GELU (tanh-form sigmoid; |err|<3e-4 << bf16 lsb)
      #pragma unroll
      for (int j=0;j<3;j++) {
        int colc = (wave*3 + j)*16 + ln15;
        #pragma unroll
        for (int mt=0;mt<4;mt++)
          #pragma unroll
          for (int r=0;r<4;r++) {
            int row = mt*16 + quad*4 + r;
            float g = acc[j][mt][r] + bb[j];
            float u = g*(1.5957691216f + 0.0713548170f*g*g);
            hidc[row*HSP + colc] = (bfr)(g / (1.f + __expf(-u)));
          }
      }
    }
    __syncthreads();
    // ---- fc2 partial: M=64, N=192, K=192 (k-range c*192..+191) ----
    // NOTE: no barrier after this; next fc1 writes the OTHER hid buffer.
    #pragma unroll
    for (int kk = 0; kk < 6; kk++) {
      bf8 afr[4];
      #pragma unroll
      for (int mt=0;mt<4;mt++)
        afr[mt] = *(const bf8*)&hidc[(mt*16+ln15)*HSP + kk*32 + quad*8];
      #pragma unroll
      for (int j=0;j<3;j++) {
        bf8 bw = *(const bf8*)&w2T[(size_t)((wave*3+j)*16 + ln15)*768
                                   + c*192 + kk*32 + quad*8];
        #pragma unroll
        for (int mt=0;mt<4;mt++) accp[j][mt] = MFMA16(afr[mt], bw, accp[j][mt]);
      }
    }
  }

  // ---- epilogue: bias -> st overlay (ts+hid0 dead: last ts read fc1(3), last hid0
  // read fc2(2), both before barrier(3); concurrent fc2(3) reads hid1, disjoint) ----
  #pragma unroll
  for (int j=0;j<3;j++) {
    int col = (wave*3+j)*16 + ln15;
    float bb2 = b2[col];
    #pragma unroll
    for (int mt=0;mt<4;mt++)
      #pragma unroll
      for (int r=0;r<4;r++) {
        int row = mt*16 + quad*4 + r;
        st[row*196 + col] = accp[j][mt][r] + bb2;
      }
  }
  __syncthreads();
  // residual, coalesced, in-place
  for (int idx = tid; idx < 64*C_; idx += 256) {
    int r = idx / C_, c = idx % C_;
    size_t gr = (size_t)(r0 + r)*C_ + c;
    y[gr] = y[gr] + st[r*196 + c];
  }
}

extern "C" void kernel_launch(void* const* d_in, const int* in_sizes, int n_in,
                              void* d_out, int out_size, void* d_ws, size_t ws_size,
                              hipStream_t stream) {
  const float* x     = (const float*)d_in[0];
  const float* n1w   = (const float*)d_in[1];
  const float* n1b   = (const float*)d_in[2];
  const float* qkvw  = (const float*)d_in[3];
  const float* qkvb  = (const float*)d_in[4];
  const float* btab  = (const float*)d_in[5];
  const float* projw = (const float*)d_in[6];
  const float* projb = (const float*)d_in[7];
  const float* n2w   = (const float*)d_in[8];
  const float* n2b   = (const float*)d_in[9];
  const float* w1    = (const float*)d_in[10];
  const float* b1    = (const float*)d_in[11];
  const float* w2    = (const float*)d_in[12];
  const float* b2    = (const float*)d_in[13];
  const float* mask  = (const float*)d_in[14];
  const int*   rel   = (const int*)d_in[15];
  float* out = (float*)d_out;
  bfr*   wsp = (bfr*)d_ws;   // (442368 + 98304) * 2 B ~= 1.08 MB

  k_prep<<<(WTOT+255)/256, 256, 0, stream>>>(qkvw, projw, w1, w2, wsp);
  k_prep2<<<(BMTOT+255)/256, 256, 0, stream>>>(btab, rel, mask, wsp + OBM);
  k_attn<<<NWIN, 256, 0, stream>>>(x, n1w, n1b, wsp, qkvb, projb, out);
  k_mlp<<<ROWS/64, 256, 0, stream>>>(out, n2w, n2b, wsp, b1, b2);
}

// Round 7
// 514.978 us; speedup vs baseline: 1.2090x; 1.0407x over previous
//
#include <hip/hip_runtime.h>
#include <math.h>

#define B_    32
#define HH    56
#define WW_   56
#define C_    192
#define WS_   7
#define SHIFT_ 3
#define HEADS_ 6
#define DH    32
#define N_    49
#define NWIN  2048
#define ROWS  100352
#define HID_  768
#define QKVN  576

typedef __bf16 bfr;
typedef __bf16 bf8 __attribute__((ext_vector_type(8)));
typedef __bf16 bf4 __attribute__((ext_vector_type(4)));
typedef float  f32x4 __attribute__((ext_vector_type(4)));

#define MFMA16(a,b,c) __builtin_amdgcn_mfma_f32_16x16x32_bf16(a,b,c,0,0,0)

// ---- ws layout (bf16 elements) ----
#define OQW   0         // qkvwT [576][192]
#define OPW   110592    // projwT[192][192]
#define OW1   147456    // w1T   [768][192]
#define OW2   294912    // w2T   [192][768]
#define OBM   442368    // bmask [6][4cls][64col][64row] TRANSPOSED (bias+mask, pads=-1e30)
#define WTOT  442368
#define BMTOT 98304     // 6*4*64*64  (4 window classes: (wh==7)x(ww==7))

// ================= k_prep: transpose + fp32->bf16 all weights =================
__global__ __launch_bounds__(256) void k_prep(
    const float* __restrict__ qkvw, const float* __restrict__ projw,
    const float* __restrict__ w1,   const float* __restrict__ w2,
    bfr* __restrict__ wsp)
{
  int idx = blockIdx.x*256 + threadIdx.x;
  if (idx >= WTOT) return;
  if (idx < OPW)      { int i=idx;      int n=i/192, k=i%192; wsp[idx] = (bfr)qkvw[k*QKVN + n]; }
  else if (idx < OW1) { int i=idx-OPW;  int n=i/192, k=i%192; wsp[idx] = (bfr)projw[k*C_ + n]; }
  else if (idx < OW2) { int i=idx-OW1;  int n=i/192, k=i%192; wsp[idx] = (bfr)w1[k*HID_ + n]; }
  else                { int i=idx-OW2;  int n=i/768, k=i%768; wsp[idx] = (bfr)w2[k*C_ + n]; }
}

// ====== k_prep2: bmask[head][cls][col64][row64] = bias + mask (pads -1e30) ======
// The shifted-window mask depends on (wh,ww) only through (wh==7, ww==7): 4 classes.
__global__ __launch_bounds__(256) void k_prep2(
    const float* __restrict__ btab, const int* __restrict__ rel,
    const float* __restrict__ mask, bfr* __restrict__ bm)
{
  int idx = blockIdx.x*256 + threadIdx.x;   // [head][cls][col][row] -- row fastest
  if (idx >= BMTOT) return;
  int row = idx & 63, col = (idx>>6) & 63, cls = (idx>>12) & 3, head = idx>>14;
  int wh = (cls & 2) ? 7 : 0, ww = (cls & 1) ? 7 : 0;
  int wi = wh*8 + ww;
  float v = -1e30f;
  if (row < N_ && col < N_) {
    int e = row*N_ + col;
    v = btab[rel[e]*HEADS_ + head] + mask[(size_t)wi*N_*N_ + e];
  }
  bm[idx] = (bfr)v;
}

// ================= Kernel 1: LN1+shift+QKV+attn+proj+residual, head-pair fused ============
// LDS (bytes):
#define SM_HS 0        // bfr hs[64][200]          25600  (LN'd input, persists)
#define SM_QS 25600    // bfr qs[2][64][36]         9216
#define SM_KS 34816    // bfr ks[2][64][36]         9216
#define SM_VT 44032    // bfr vT[2][32][72]         9216
#define SM_P  53248    // bfr P[64][72]             9216  (wave-row-local scratch)
#define SM_OV 62464    // bfr ov2[64][72]           9216  (both heads: [row][hl*36+d])
#define SM_SR 71680    // int srows[64]              256
#define SM1_TOT 71936
#define HSP 200

__global__ __launch_bounds__(256, 2) void k_attn(
    const float* __restrict__ x,
    const float* __restrict__ n1w, const float* __restrict__ n1b,
    const bfr*   __restrict__ wsp,
    const float* __restrict__ qkvb,
    const float* __restrict__ projb,
    float* __restrict__ out)
{
  __shared__ char smem[SM1_TOT];
  bfr*   hs    = (bfr*)(smem + SM_HS);
  bfr*   qs    = (bfr*)(smem + SM_QS);
  bfr*   ks    = (bfr*)(smem + SM_KS);
  bfr*   vT    = (bfr*)(smem + SM_VT);
  bfr*   P     = (bfr*)(smem + SM_P);
  bfr*   ov2   = (bfr*)(smem + SM_OV);
  int*   srows = (int*)(smem + SM_SR);
  float* pj    = (float*)smem;   // overlay [64][196] fp32 = 50176 B over hs/qs/ks/vT

  const f32x4 ZERO4 = {0.f, 0.f, 0.f, 0.f};

  int win  = blockIdx.x;
  int tid  = threadIdx.x;
  int lane = tid & 63, wave = tid >> 6;
  int ln15 = lane & 15, quad = lane >> 4;
  int wi   = win & 63;
  int cls  = (((wi>>3)==7) ? 2 : 0) + (((wi&7)==7) ? 1 : 0);

  // ---- srows + zero hs pad rows (49..63 only) ----
  if (tid < N_) {
    int bb = win >> 6;
    int wh = wi >> 3, ww = wi & 7;
    int th = tid / WS_, tw = tid % WS_;
    int sh = wh*WS_ + th + SHIFT_; if (sh >= HH) sh -= HH;
    int sw = ww*WS_ + tw + SHIFT_; if (sw >= WW_) sw -= WW_;
    srows[tid] = bb*HH*WW_ + sh*WW_ + sw;
  }
  {
    int* hz = (int*)(hs + 49*HSP);
    for (int i = tid; i < 15*HSP/2; i += 256) hz[i] = 0;
  }
  __syncthreads();
  // ---- LN1 -> hs ----
  for (int r = wave; r < N_; r += 4) {
    const float* xr = x + (size_t)srows[r]*C_;
    float v0 = xr[lane], v1 = xr[lane+64], v2 = xr[lane+128];
    float s = v0+v1+v2, q = v0*v0+v1*v1+v2*v2;
    #pragma unroll
    for (int m = 32; m; m >>= 1) { s += __shfl_xor(s, m); q += __shfl_xor(q, m); }
    float mu = s*(1.f/C_), var = q*(1.f/C_) - mu*mu;
    float rs = rsqrtf(var + 1e-5f);
    hs[r*HSP + lane]     = (bfr)((v0-mu)*rs*n1w[lane]     + n1b[lane]);
    hs[r*HSP + lane+64]  = (bfr)((v1-mu)*rs*n1w[lane+64]  + n1b[lane+64]);
    hs[r*HSP + lane+128] = (bfr)((v2-mu)*rs*n1w[lane+128] + n1b[lane+128]);
  }
  __syncthreads();

  const bfr* qkvwT  = wsp + OQW;
  const bfr* projwT = wsp + OPW;
  const bfr* bmask  = wsp + OBM;

  f32x4 accp[3][4];   // proj accumulators, persist across pairs
  #pragma unroll
  for (int j=0;j<3;j++)
    #pragma unroll
    for (int mt=0;mt<4;mt++) accp[j][mt] = ZERO4;

  for (int pair = 0; pair < 3; pair++) {
    // ---- QKV phase: wave handles col-tile (wave) of q(j=0),k(j=1),v(j=2) ----
    {
      float qb[3];
      #pragma unroll
      for (int j=0;j<3;j++) qb[j] = qkvb[j*192 + pair*64 + wave*16 + ln15];
      f32x4 acc[3][4];
      #pragma unroll
      for (int j=0;j<3;j++)
        #pragma unroll
        for (int mt=0;mt<4;mt++) acc[j][mt] = ZERO4;
      #pragma unroll
      for (int kk = 0; kk < 6; kk++) {
        bf8 afr[4];
        #pragma unroll
        for (int mt=0;mt<4;mt++)
          afr[mt] = *(const bf8*)&hs[(mt*16+ln15)*HSP + kk*32 + quad*8];
        #pragma unroll
        for (int j=0;j<3;j++) {
          bf8 bw = *(const bf8*)&qkvwT[(size_t)(j*192 + pair*64 + wave*16 + ln15)*192
                                       + kk*32 + quad*8];
          #pragma unroll
          for (int mt=0;mt<4;mt++) acc[j][mt] = MFMA16(afr[mt], bw, acc[j][mt]);
        }
      }
      int colp = wave*16 + ln15;         // within-pair col 0..63
      int hl = colp >> 5, d = colp & 31;
      #pragma unroll
      for (int j=0;j<3;j++) {
        #pragma unroll
        for (int mt=0;mt<4;mt++)
          #pragma unroll
          for (int r=0;r<4;r++) {
            int row = mt*16 + quad*4 + r;
            float vv = acc[j][mt][r] + qb[j];
            if (j == 0)      qs[(hl*64+row)*36 + d] = (bfr)(vv*0.17677669529663689f);
            else if (j == 1) ks[(hl*64+row)*36 + d] = (bfr)vv;
            else             vT[(hl*32+d)*72 + row] = (bfr)vv;
          }
      }
    }
    __syncthreads();

    // ---- bmask burst (both heads, 8x 8B loads; 192KB table -> L2-resident) ----
    bf4 bm4[2][4];
    #pragma unroll
    for (int hl = 0; hl < 2; hl++) {
      const bfr* bmh = bmask + (((size_t)(pair*2+hl)*4 + cls) << 12);  // [col64][row64]
      #pragma unroll
      for (int nt = 0; nt < 4; nt++)
        bm4[hl][nt] = *(const bf4*)&bmh[(nt*16 + ln15)*64 + wave*16 + quad*4];
    }

    // ---- QK^T for BOTH heads, bias+mask as MFMA C-init ----
    float val[2][4][4];   // [hl][nt][r]
    #pragma unroll
    for (int hl = 0; hl < 2; hl++) {
      bf8 aq = *(const bf8*)&qs[(hl*64 + wave*16 + ln15)*36 + quad*8];
      #pragma unroll
      for (int nt = 0; nt < 4; nt++) {
        f32x4 c;
        c[0] = (float)bm4[hl][nt][0]; c[1] = (float)bm4[hl][nt][1];
        c[2] = (float)bm4[hl][nt][2]; c[3] = (float)bm4[hl][nt][3];
        bf8 bk = *(const bf8*)&ks[(hl*64 + nt*16 + ln15)*36 + quad*8];
        c = MFMA16(aq, bk, c);
        #pragma unroll
        for (int r=0;r<4;r++) val[hl][nt][r] = c[r];
      }
    }

    // ---- proj-weight prefetch (6x 16B): latency hides under softmax ----
    bf8 pw[2][3];
    #pragma unroll
    for (int hl = 0; hl < 2; hl++)
      #pragma unroll
      for (int j = 0; j < 3; j++)
        pw[hl][j] = *(const bf8*)&projwT[(size_t)((wave*3+j)*16 + ln15)*192
                                         + (pair*2+hl)*32 + quad*8];

    // ---- per head: register softmax + P (wave-row-local, NO barrier) + PV -> ov2 ----
    #pragma unroll
    for (int hl = 0; hl < 2; hl++) {
      float mx[4], sum[4];
      #pragma unroll
      for (int r=0;r<4;r++) {
        mx[r] = fmaxf(fmaxf(val[hl][0][r], val[hl][1][r]), fmaxf(val[hl][2][r], val[hl][3][r]));
        #pragma unroll
        for (int m = 1; m < 16; m <<= 1) mx[r] = fmaxf(mx[r], __shfl_xor(mx[r], m));
      }
      #pragma unroll
      for (int nt=0;nt<4;nt++)
        #pragma unroll
        for (int r=0;r<4;r++) val[hl][nt][r] = __expf(val[hl][nt][r] - mx[r]);
      #pragma unroll
      for (int r=0;r<4;r++) {
        sum[r] = val[hl][0][r] + val[hl][1][r] + val[hl][2][r] + val[hl][3][r];
        #pragma unroll
        for (int m = 1; m < 16; m <<= 1) sum[r] += __shfl_xor(sum[r], m);
        sum[r] = 1.f / sum[r];
      }
      #pragma unroll
      for (int nt=0;nt<4;nt++)
        #pragma unroll
        for (int r=0;r<4;r++)
          P[(wave*16 + quad*4 + r)*72 + nt*16 + ln15] = (bfr)(val[hl][nt][r]*sum[r]);
      // PV: wave reads ONLY its own P rows -> in-wave lgkmcnt dep, no barrier
      #pragma unroll
      for (int nt = 0; nt < 2; nt++) {
        f32x4 c = ZERO4;
        #pragma unroll
        for (int k0 = 0; k0 < 64; k0 += 32) {
          bf8 ap = *(const bf8*)&P[(wave*16 + ln15)*72 + k0 + quad*8];
          bf8 bv = *(const bf8*)&vT[(hl*32 + nt*16 + ln15)*72 + k0 + quad*8];
          c = MFMA16(ap, bv, c);
        }
        #pragma unroll
        for (int r=0;r<4;r++)
          ov2[(wave*16 + quad*4 + r)*72 + hl*36 + nt*16 + ln15] = (bfr)c[r];
      }
    }
    __syncthreads();

    // ---- proj K-step for this pair (K=64: both heads), weights already in regs ----
    #pragma unroll
    for (int hl = 0; hl < 2; hl++) {
      bf8 afr[4];
      #pragma unroll
      for (int mt=0;mt<4;mt++)
        afr[mt] = *(const bf8*)&ov2[(mt*16+ln15)*72 + hl*36 + quad*8];
      #pragma unroll
      for (int j=0;j<3;j++)
        #pragma unroll
        for (int mt=0;mt<4;mt++) accp[j][mt] = MFMA16(afr[mt], pw[hl][j], accp[j][mt]);
    }
    // no barrier: next pair's QKV writes qs/ks/vT; all reads of them finished pre-ov2-barrier
  }

  // ---- epilogue: bias -> pj overlay -> coalesced residual+scatter ----
  __syncthreads();   // all waves past last proj before pj overlays hs..vT
  #pragma unroll
  for (int j=0;j<3;j++) {
    int col = (wave*3+j)*16 + ln15;
    float pb = projb[col];
    #pragma unroll
    for (int mt=0;mt<4;mt++)
      #pragma unroll
      for (int r=0;r<4;r++)
        pj[(mt*16 + quad*4 + r)*196 + col] = accp[j][mt][r] + pb;
  }
  __syncthreads();
  for (int idx = tid; idx < N_*C_; idx += 256) {
    int n = idx / C_, c = idx % C_;
    size_t gr = (size_t)srows[n]*C_ + c;
    out[gr] = x[gr] + pj[n*196 + c];
  }
}

// ================= Kernel 2: LN2 + fc1 + GELU + fc2 + residual, 64 rows/block ================
// LDS: ts[64][200] bf16 (25600) + hidc[64][200] bf16 (25600) = 51200 B -> 3 blocks/CU.
// st f32[64][196] (50176) overlays ts+hidc after last use.
#define SM2_TS  0
#define SM2_HID 25600
#define SM2_TOT 51200

__global__ __launch_bounds__(256, 2) void k_mlp(
    float* __restrict__ y,
    const float* __restrict__ n2w, const float* __restrict__ n2b,
    const bfr* __restrict__ wsp,
    const float* __restrict__ b1, const float* __restrict__ b2)
{
  __shared__ char smem[SM2_TOT];
  bfr*   ts   = (bfr*)(smem + SM2_TS);
  bfr*   hidc = (bfr*)(smem + SM2_HID);
  float* st   = (float*)smem;       // overlay after ts/hidc dead

  const f32x4 ZERO4 = {0.f, 0.f, 0.f, 0.f};

  int r0 = blockIdx.x * 64;
  int tid = threadIdx.x;
  int lane = tid & 63, wave = tid >> 6;
  int ln15 = lane & 15, quad = lane >> 4;

  // ---- LN2 ----
  #pragma unroll
  for (int i = 0; i < 16; i++) {
    int r = wave + i*4;
    const float* yr = y + (size_t)(r0 + r)*C_;
    float v0 = yr[lane], v1 = yr[lane+64], v2 = yr[lane+128];
    float s = v0+v1+v2, q = v0*v0+v1*v1+v2*v2;
    #pragma unroll
    for (int m = 32; m; m >>= 1) { s += __shfl_xor(s, m); q += __shfl_xor(q, m); }
    float mu = s*(1.f/C_), var = q*(1.f/C_) - mu*mu;
    float rs = rsqrtf(var + 1e-5f);
    ts[r*HSP + lane]     = (bfr)((v0-mu)*rs*n2w[lane]     + n2b[lane]);
    ts[r*HSP + lane+64]  = (bfr)((v1-mu)*rs*n2w[lane+64]  + n2b[lane+64]);
    ts[r*HSP + lane+128] = (bfr)((v2-mu)*rs*n2w[lane+128] + n2b[lane+128]);
  }
  __syncthreads();

  const bfr* w1T = wsp + OW1;
  const bfr* w2T = wsp + OW2;

  f32x4 accp[3][4];   // fc2 accumulators, persist across chunks
  #pragma unroll
  for (int j=0;j<3;j++)
    #pragma unroll
    for (int mt=0;mt<4;mt++) accp[j][mt] = ZERO4;

  for (int c = 0; c < 4; c++) {
    // ---- fc1 weight burst (18x 16B) + b1 prefetch ----
    bf8 wf1[3][6];
    float bb[3];
    #pragma unroll
    for (int j=0;j<3;j++) {
      const bfr* wb = w1T + (size_t)((c*12 + wave*3 + j)*16 + ln15)*192 + quad*8;
      #pragma unroll
      for (int kk=0;kk<6;kk++)
        wf1[j][kk] = *(const bf8*)&wb[kk*32];
      bb[j] = b1[c*192 + (wave*3+j)*16 + ln15];
    }
    // ---- fc1 chunk: M=64, N=192, K=192, weights from regs ----
    f32x4 acc[3][4];
    #pragma unroll
    for (int j=0;j<3;j++)
      #pragma unroll
      for (int mt=0;mt<4;mt++) acc[j][mt] = ZERO4;
    #pragma unroll
    for (int kk = 0; kk < 6; kk++) {
      bf8 afr[4];
      #pragma unroll
      for (int mt=0;mt<4;mt++)
        afr[mt] = *(const bf8*)&ts[(mt*16+ln15)*HSP + kk*32 + quad*8];
      #pragma unroll
      for (int j=0;j<3;j++)
        #pragma unroll
        for (int mt=0;mt<4;mt++) acc[j][mt] = MFMA16(afr[mt], wf1[j][kk], acc[j][mt]);
    }
    // ---- fc2 weight burst issued per-j BEFORE that j's GELU (latency hides under VALU) ----
    bf8 wf2[3][6];
    #pragma unroll
    for (int j=0;j<3;j++) {
      const bfr* wb2 = w2T + (size_t)((wave*3+j)*16 + ln15)*768 + c*192 + quad*8;
      #pragma unroll
      for (int kk=0;kk<6;kk++)
        wf2[j][kk] = *(const bf8*)&wb2[kk*32];
      // GELU (tanh-form sigmoid; |err|<3e-4 << bf16 lsb)
      int colc = (wave*3 + j)*16 + ln15;
      #pragma unroll
      for (int mt=0;mt<4;mt++)
        #pragma unroll
        for (int r=0;r<4;r++) {
          int row = mt*16 + quad*4 + r;
          float g = acc[j][mt][r] + bb[j];
          float u = g*(1.5957691216f + 0.0713548170f*g*g);
          hidc[row*HSP + colc] = (bfr)(g / (1.f + __expf(-u)));
        }
    }
    __syncthreads();
    // ---- fc2 partial: M=64, N=192, K=192, weights from regs ----
    #pragma unroll
    for (int kk = 0; kk < 6; kk++) {
      bf8 afr[4];
      #pragma unroll
      for (int mt=0;mt<4;mt++)
        afr[mt] = *(const bf8*)&hidc[(mt*16+ln15)*HSP + kk*32 + quad*8];
      #pragma unroll
      for (int j=0;j<3;j++)
        #pragma unroll
        for (int mt=0;mt<4;mt++) accp[j][mt] = MFMA16(afr[mt], wf2[j][kk], accp[j][mt]);
    }
    __syncthreads();   // hidc reads done before next chunk's writes (or st overlay)
  }

  // ---- epilogue: bias -> st overlay (over ts/hidc, both dead) ----
  #pragma unroll
  for (int j=0;j<3;j++) {
    int col = (wave*3+j)*16 + ln15;
    float bb2 = b2[col];
    #pragma unroll
    for (int mt=0;mt<4;mt++)
      #pragma unroll
      for (int r=0;r<4;r++) {
        int row = mt*16 + quad*4 + r;
        st[row*196 + col] = accp[j][mt][r] + bb2;
      }
  }
  __syncthreads();
  // residual, coalesced, in-place
  for (int idx = tid; idx < 64*C_; idx += 256) {
    int r = idx / C_, c = idx % C_;
    size_t gr = (size_t)(r0 + r)*C_ + c;
    y[gr] = y[gr] + st[r*196 + c];
  }
}

extern "C" void kernel_launch(void* const* d_in, const int* in_sizes, int n_in,
                              void* d_out, int out_size, void* d_ws, size_t ws_size,
                              hipStream_t stream) {
  const float* x     = (const float*)d_in[0];
  const float* n1w   = (const float*)d_in[1];
  const float* n1b   = (const float*)d_in[2];
  const float* qkvw  = (const float*)d_in[3];
  const float* qkvb  = (const float*)d_in[4];
  const float* btab  = (const float*)d_in[5];
  const float* projw = (const float*)d_in[6];
  const float* projb = (const float*)d_in[7];
  const float* n2w   = (const float*)d_in[8];
  const float* n2b   = (const float*)d_in[9];
  const float* w1    = (const float*)d_in[10];
  const float* b1    = (const float*)d_in[11];
  const float* w2    = (const float*)d_in[12];
  const float* b2    = (const float*)d_in[13];
  const float* mask  = (const float*)d_in[14];
  const int*   rel   = (const int*)d_in[15];
  float* out = (float*)d_out;
  bfr*   wsp = (bfr*)d_ws;   // (442368 + 98304) * 2 B ~= 1.08 MB

  k_prep<<<(WTOT+255)/256, 256, 0, stream>>>(qkvw, projw, w1, w2, wsp);
  k_prep2<<<(BMTOT+255)/256, 256, 0, stream>>>(btab, rel, mask, wsp + OBM);
  k_attn<<<NWIN, 256, 0, stream>>>(x, n1w, n1b, wsp, qkvb, projb, out);
  k_mlp<<<ROWS/64, 256, 0, stream>>>(out, n2w, n2b, wsp, b1, b2);
}